// Round 10
// baseline (37339.053 us; speedup 1.0000x reference)
//
#include <hip/hip_runtime.h>
#include <hip/hip_fp16.h>

// B=64, T=512, D=96, H=256
constexpr int Tt = 512, Dd = 96, Hh = 256;
constexpr int NS0 = 16;   // h0 ring depth
constexpr int NSP = 8;    // P ring depth
typedef unsigned long long u64;

// ws byte offsets:
//  [0,4MB):   h0 rings: (chain*16+rg) x NS0 slots x 1024 tagged u64
//  [4,12MB):  P0 rings: (chain*16+rg) x NSP slots x 4096 tagged u64
//  [12,20MB): P1 rings, same shape
//  [20MB, +16KB): flags
//  [20MB+64KB, +3MB): fp16-paired weights
constexpr size_t OFF_P0  = (size_t)4 << 20;
constexpr size_t OFF_P1  = (size_t)12 << 20;
constexpr size_t OFF_FLG = (size_t)20 << 20;
constexpr size_t OFF_W16 = ((size_t)20 << 20) + ((size_t)64 << 10);
constexpr size_t oGW0 = 0;
constexpr size_t oGU0 = oGW0 + (size_t)48 * 768;
constexpr size_t oGW1 = oGU0 + (size_t)128 * 768;
constexpr size_t oGU1 = oGW1 + (size_t)128 * 768;
constexpr size_t oLW0 = oGU1 + (size_t)128 * 768;
constexpr size_t oLU0 = oLW0 + (size_t)48 * 1024;
constexpr size_t oLW1 = oLU0 + (size_t)128 * 1024;
constexpr size_t oLU1 = oLW1 + (size_t)128 * 1024;

__device__ __forceinline__ float sigf(float v) { return 1.0f / (1.0f + __expf(-v)); }
__device__ __forceinline__ u64 agld(const u64* p) {
    return __hip_atomic_load(p, __ATOMIC_RELAXED, __HIP_MEMORY_SCOPE_AGENT);
}
__device__ __forceinline__ int agldi(const int* p) {
    return __hip_atomic_load(p, __ATOMIC_ACQUIRE, __HIP_MEMORY_SCOPE_AGENT);
}

// fp16x2 dot into f32 accumulator
__device__ __forceinline__ float dot2f(unsigned w, unsigned a, float acc) {
#if __has_builtin(__builtin_amdgcn_fdot2)
    typedef _Float16 h2v __attribute__((ext_vector_type(2)));
    h2v wh, ah;
    __builtin_memcpy(&wh, &w, 4);
    __builtin_memcpy(&ah, &a, 4);
    return __builtin_amdgcn_fdot2(wh, ah, acc, false);
#else
    const float2 wf = __half22float2(*(const __half2*)&w);
    const float2 af = __half22float2(*(const __half2*)&a);
    acc = fmaf(wf.x, af.x, acc);
    return fmaf(wf.y, af.y, acc);
#endif
}

// GEMM: G gate streams x 4 rows; 8-kp chunks, depth-2 register pipeline.
// Mc pre-offset by column c; ldm = GAH; A = sAh as uint4[kp] (4 rows' half2).
template<int G>
__device__ __forceinline__ void gemm8(const unsigned* __restrict__ Mc, int ldm,
                                      const unsigned* __restrict__ sAh,
                                      int kp0, int nchunk, float4* acc) {
    unsigned wv[2][8 * G];
    uint4    av[2][8];
    const uint4* A4 = (const uint4*)sAh;
    #pragma unroll
    for (int u = 0; u < 8; ++u) {
        const int kp = kp0 + u;
        av[0][u] = A4[kp];
        #pragma unroll
        for (int g = 0; g < G; ++g)
            wv[0][u * G + g] = Mc[(size_t)kp * ldm + g * 256];
    }
    for (int ch = 0; ch < nchunk; ++ch) {
        const int cur = ch & 1, nxt = cur ^ 1;
        if (ch + 1 < nchunk) {
            const int kpb = kp0 + (ch + 1) * 8;
            #pragma unroll
            for (int u = 0; u < 8; ++u) {
                av[nxt][u] = A4[kpb + u];
                #pragma unroll
                for (int g = 0; g < G; ++g)
                    wv[nxt][u * G + g] = Mc[(size_t)(kpb + u) * ldm + g * 256];
            }
        }
        #pragma unroll
        for (int u = 0; u < 8; ++u) {
            const uint4 a = av[cur][u];
            #pragma unroll
            for (int g = 0; g < G; ++g) {
                const unsigned w = wv[cur][u * G + g];
                acc[g].x = dot2f(w, a.x, acc[g].x);
                acc[g].y = dot2f(w, a.y, acc[g].y);
                acc[g].z = dot2f(w, a.z, acc[g].z);
                acc[g].w = dot2f(w, a.w, acc[g].w);
            }
        }
    }
}

// weight f32 -> paired fp16 (per launch)
__global__ void cvt_pair(const float* __restrict__ src, unsigned* __restrict__ dst,
                         int n, int ld) {
    const int i = blockIdx.x * 256 + threadIdx.x;
    if (i >= n) return;
    const int kp = i / ld, col = i - kp * ld;
    const __half2 h = __floats2half2_rn(src[(2 * kp) * ld + col],
                                        src[(2 * kp + 1) * ld + col]);
    dst[i] = *(const unsigned*)&h;
}

// roles: 0 = p0 (x->P0), 1 = r0 (U0 + h0 update), 2 = p1 (h0->P1), 3 = r1 (U1 + head)
// bx = (chain*4+role) + 8*rg
__global__ void __launch_bounds__(512, 1)
rnn_persist(const float* __restrict__ x, const int* __restrict__ lengths,
            const float* __restrict__ gbi0, const float* __restrict__ gbr0,
            const float* __restrict__ gbi1, const float* __restrict__ gbr1,
            const float* __restrict__ lb0, const float* __restrict__ lb1,
            const float* __restrict__ outW, const float* __restrict__ outb,
            float* __restrict__ out, char* __restrict__ wsb)
{
    const int tid = threadIdx.x;
    const int c   = tid & 255;
    const int grp = tid >> 8;
    const int bx  = blockIdx.x;
    const int role  = bx & 3;
    const int chain = (bx >> 2) & 1;
    const int rg    = bx >> 3;
    const int rowbase = rg * 4;

    const int GA  = chain ? 4 : 3;
    const int GAH = GA * Hh;

    u64* h0ring = (u64*)wsb + (size_t)(chain * 16 + rg) * (NS0 * 1024);
    u64* p0ring = (u64*)(wsb + OFF_P0) + (size_t)(chain * 16 + rg) * (NSP * 4096);
    u64* p1ring = (u64*)(wsb + OFF_P1) + (size_t)(chain * 16 + rg) * (NSP * 4096);
    int* flags = (int*)(wsb + OFF_FLG);
    int* flg_r0 = flags + ((chain * 16 + rg) * 4 + 1) * 32;
    int* flg_p1 = flags + ((chain * 16 + rg) * 4 + 2) * 32;
    int* flg_r1 = flags + ((chain * 16 + rg) * 4 + 3) * 32;

    const unsigned* W16 = (const unsigned*)(wsb + OFF_W16);
    size_t woff;
    if (chain == 0) woff = (role == 0) ? oGW0 : (role == 1) ? oGU0 : (role == 2) ? oGW1 : oGU1;
    else            woff = (role == 0) ? oLW0 : (role == 1) ? oLU0 : (role == 2) ? oLW1 : oLU1;
    const unsigned* Mc = W16 + woff + c;

    const int KR  = (role == 0) ? Dd : Hh;
    const int KP2 = KR >> 2;                 // kp per group (24 or 64)
    const int kp0 = grp * KP2;
    const int nch = KP2 >> 3;                // chunks (3 or 8)

    __shared__ __align__(16) unsigned sAh[128 * 4];   // [kp][4 rows] half2
    __shared__ float sG[2 * 4096];
    __shared__ float sP[4096];
    __shared__ float sRed[16];
    __half* sAhh = (__half*)sAh;

    const int NP  = 4 * GAH;
    const int npt = NP >> 9;                 // 6 or 8
    float biasv[8];
    int sgidx[8];
    if (role == 0 || role == 2) {
        const float* bsrc = (chain == 0) ? (role == 0 ? gbi0 : gbi1)
                                         : (role == 0 ? lb0 : lb1);
        #pragma unroll
        for (int i = 0; i < 8; ++i) {
            if (i < npt) {
                const int e = tid + i * 512;
                const int r = e / GAH, rem = e - r * GAH;
                biasv[i] = bsrc[rem];
                sgidx[i] = r * 1024 + rem;
            } else { biasv[i] = 0; sgidx[i] = 0; }
        }
    }
    const int rA = tid >> 8;                 // rows rA, rA+2
    const int lenA = lengths[rowbase + rA];
    const int lenB = lengths[rowbase + rA + 2];
    float brz = 0, brr = 0, brh = 0, ow = 0;
    if (chain == 0 && (role == 1 || role == 3)) {
        const float* br = (role == 1) ? gbr0 : gbr1;
        brz = br[c]; brr = br[Hh + c]; brh = br[2 * Hh + c];
    }
    if (role == 3) ow = outW[chain * Hh + c];
    const float outb0 = outb[0];
    float creg0 = 0.0f, creg1 = 0.0f;
    float hprev0 = 0.0f, hprev1 = 0.0f;      // own h(t-1), rows rA / rA+2

    for (int i = tid; i < 512; i += 512) sAh[i] = 0;   // h(-1)=0 (also fp16 zero)
    __syncthreads();

    for (int t = 0; t < Tt; ++t) {
        if (role == 0) {
            // ---- p0: anti-clobber + stage x (fp16) ----
            if (t >= NSP && tid == 0)
                while (agldi(flg_r0) < t - NSP + 1) __builtin_amdgcn_s_sleep(1);
            if (tid < 4 * Dd) {
                const int r = tid / Dd, k = tid - r * Dd;
                const float v = x[((size_t)(rowbase + r) * Tt + t) * Dd + k];
                sAhh[(k >> 1) * 8 + r * 2 + (k & 1)] = __float2half(v);
            }
            __syncthreads();
            if (chain == 0) {
                float4 acc[3] = {{0,0,0,0},{0,0,0,0},{0,0,0,0}};
                gemm8<3>(Mc, GAH, sAh, kp0, nch, acc);
                #pragma unroll
                for (int g = 0; g < 3; ++g) {
                    sG[grp * 4096 + 0 + g * 256 + c]    = acc[g].x;
                    sG[grp * 4096 + 1024 + g * 256 + c] = acc[g].y;
                    sG[grp * 4096 + 2048 + g * 256 + c] = acc[g].z;
                    sG[grp * 4096 + 3072 + g * 256 + c] = acc[g].w;
                }
            } else {
                float4 acc[4] = {{0,0,0,0},{0,0,0,0},{0,0,0,0},{0,0,0,0}};
                gemm8<4>(Mc, GAH, sAh, kp0, nch, acc);
                #pragma unroll
                for (int g = 0; g < 4; ++g) {
                    sG[grp * 4096 + 0 + g * 256 + c]    = acc[g].x;
                    sG[grp * 4096 + 1024 + g * 256 + c] = acc[g].y;
                    sG[grp * 4096 + 2048 + g * 256 + c] = acc[g].z;
                    sG[grp * 4096 + 3072 + g * 256 + c] = acc[g].w;
                }
            }
            __syncthreads();
            u64* slot = p0ring + (size_t)(t & (NSP - 1)) * 4096;
            for (int i = 0; i < npt; ++i) {
                const float v = sG[sgidx[i]] + sG[4096 + sgidx[i]] + biasv[i];
                atomicExch(slot + tid + i * 512,
                           ((u64)__float_as_uint(v) << 32) | (unsigned)(t + 1));
            }
        } else if (role == 2) {
            // ---- p1: poll h0(t) -> sAh(fp16), GEMM, publish P1 ----
            {
                const u64* base = h0ring + (size_t)(t & (NS0 - 1)) * 1024;
                const unsigned want = (unsigned)(t + 1);
                const int r0i = rA, r1i = rA + 2;
                const u64* p0 = base + r0i * 256 + c;
                const u64* p1 = base + r1i * 256 + c;
                u64 v0 = 0, v1 = 0; bool d0 = false, d1 = false;
                do {
                    if (!d0) { v0 = agld(p0); d0 = ((unsigned)v0 == want); }
                    if (!d1) { v1 = agld(p1); d1 = ((unsigned)v1 == want); }
                } while (!(d0 && d1));
                sAhh[(c >> 1) * 8 + r0i * 2 + (c & 1)] =
                    __float2half(__uint_as_float((unsigned)(v0 >> 32)));
                sAhh[(c >> 1) * 8 + r1i * 2 + (c & 1)] =
                    __float2half(__uint_as_float((unsigned)(v1 >> 32)));
            }
            if (t >= NSP && tid == 0)
                while (agldi(flg_r1) < t - NSP + 1) __builtin_amdgcn_s_sleep(1);
            __syncthreads();
            if (tid == 0)
                __hip_atomic_exchange(flg_p1, t + 1, __ATOMIC_RELEASE,
                                      __HIP_MEMORY_SCOPE_AGENT);
            if (chain == 0) {
                float4 acc[3] = {{0,0,0,0},{0,0,0,0},{0,0,0,0}};
                gemm8<3>(Mc, GAH, sAh, kp0, nch, acc);
                #pragma unroll
                for (int g = 0; g < 3; ++g) {
                    sG[grp * 4096 + 0 + g * 256 + c]    = acc[g].x;
                    sG[grp * 4096 + 1024 + g * 256 + c] = acc[g].y;
                    sG[grp * 4096 + 2048 + g * 256 + c] = acc[g].z;
                    sG[grp * 4096 + 3072 + g * 256 + c] = acc[g].w;
                }
            } else {
                float4 acc[4] = {{0,0,0,0},{0,0,0,0},{0,0,0,0},{0,0,0,0}};
                gemm8<4>(Mc, GAH, sAh, kp0, nch, acc);
                #pragma unroll
                for (int g = 0; g < 4; ++g) {
                    sG[grp * 4096 + 0 + g * 256 + c]    = acc[g].x;
                    sG[grp * 4096 + 1024 + g * 256 + c] = acc[g].y;
                    sG[grp * 4096 + 2048 + g * 256 + c] = acc[g].z;
                    sG[grp * 4096 + 3072 + g * 256 + c] = acc[g].w;
                }
            }
            __syncthreads();
            u64* slot = p1ring + (size_t)(t & (NSP - 1)) * 4096;
            for (int i = 0; i < npt; ++i) {
                const float v = sG[sgidx[i]] + sG[4096 + sgidx[i]] + biasv[i];
                atomicExch(slot + tid + i * 512,
                           ((u64)__float_as_uint(v) << 32) | (unsigned)(t + 1));
            }
        } else {
            // ---- r0 / r1: GEMM first (own h(t-1) resident in sAh) ----
            if (chain == 0) {
                float4 acc[3] = {{0,0,0,0},{0,0,0,0},{0,0,0,0}};
                gemm8<3>(Mc, GAH, sAh, kp0, nch, acc);
                #pragma unroll
                for (int g = 0; g < 3; ++g) {
                    sG[grp * 4096 + 0 + g * 256 + c]    = acc[g].x;
                    sG[grp * 4096 + 1024 + g * 256 + c] = acc[g].y;
                    sG[grp * 4096 + 2048 + g * 256 + c] = acc[g].z;
                    sG[grp * 4096 + 3072 + g * 256 + c] = acc[g].w;
                }
            } else {
                float4 acc[4] = {{0,0,0,0},{0,0,0,0},{0,0,0,0},{0,0,0,0}};
                gemm8<4>(Mc, GAH, sAh, kp0, nch, acc);
                #pragma unroll
                for (int g = 0; g < 4; ++g) {
                    sG[grp * 4096 + 0 + g * 256 + c]    = acc[g].x;
                    sG[grp * 4096 + 1024 + g * 256 + c] = acc[g].y;
                    sG[grp * 4096 + 2048 + g * 256 + c] = acc[g].z;
                    sG[grp * 4096 + 3072 + g * 256 + c] = acc[g].w;
                }
            }
            __syncthreads();   // sG done; sAh reads done

            // poll P(t) -> sP
            {
                const u64* slot = ((role == 1) ? p0ring : p1ring)
                                  + (size_t)(t & (NSP - 1)) * 4096;
                const unsigned want = (unsigned)(t + 1);
                unsigned dm = 0;
                const unsigned full = (1u << npt) - 1u;
                while (dm != full) {
                    for (int i = 0; i < npt; ++i) {
                        if (!(dm & (1u << i))) {
                            const u64 v = agld(slot + tid + i * 512);
                            if ((unsigned)v == want) {
                                sP[tid + i * 512] = __uint_as_float((unsigned)(v >> 32));
                                dm |= 1u << i;
                            }
                        }
                    }
                }
            }
            if (role == 1 && t >= NS0 && tid == 0)
                while (agldi(flg_p1) < t - NS0 + 1) __builtin_amdgcn_s_sleep(1);
            __syncthreads();   // sP complete + anti-clobber done
            if (tid == 0)
                __hip_atomic_exchange((role == 1) ? flg_r0 : flg_r1, t + 1,
                                      __ATOMIC_RELEASE, __HIP_MEMORY_SCOPE_AGENT);

            // update
            float vh0 = 0.0f, vh1 = 0.0f;
            #pragma unroll
            for (int e = 0; e < 2; ++e) {
                const int r = rA + e * 2;
                const float hold = e ? hprev1 : hprev0;
                const int len = e ? lenB : lenA;
                float hn;
                if (chain == 0) {
                    const float Pz = sP[r * GAH + c];
                    const float Pr = sP[r * GAH + Hh + c];
                    const float Ph = sP[r * GAH + 2 * Hh + c];
                    const float Qz = sG[r * 1024 + c]       + sG[4096 + r * 1024 + c];
                    const float Qr = sG[r * 1024 + 256 + c] + sG[4096 + r * 1024 + 256 + c];
                    const float Qh = sG[r * 1024 + 512 + c] + sG[4096 + r * 1024 + 512 + c];
                    const float z  = sigf(Pz + Qz + brz);
                    const float rr = sigf(Pr + Qr + brr);
                    const float hh = tanhf(Ph + rr * (Qh + brh));
                    hn = z * hold + (1.0f - z) * hh;
                    if (t >= len) hn = hold;
                } else {
                    const float gi = sP[r * GAH + c]          + sG[r * 1024 + c]       + sG[4096 + r * 1024 + c];
                    const float gf = sP[r * GAH + Hh + c]     + sG[r * 1024 + 256 + c] + sG[4096 + r * 1024 + 256 + c];
                    const float gc = sP[r * GAH + 2 * Hh + c] + sG[r * 1024 + 512 + c] + sG[4096 + r * 1024 + 512 + c];
                    const float go = sP[r * GAH + 3 * Hh + c] + sG[r * 1024 + 768 + c] + sG[4096 + r * 1024 + 768 + c];
                    const float cold = e ? creg1 : creg0;
                    float cn = sigf(gf) * cold + sigf(gi) * tanhf(gc);
                    hn = sigf(go) * tanhf(cn);
                    if (t >= len) { hn = hold; cn = cold; }
                    if (e) creg1 = cn; else creg0 = cn;
                }
                if (e) hprev1 = hn; else hprev0 = hn;
                sAhh[(c >> 1) * 8 + r * 2 + (c & 1)] = __float2half(hn);
                if (role == 1) {
                    __hip_atomic_exchange(
                        h0ring + (size_t)(t & (NS0 - 1)) * 1024 + r * 256 + c,
                        ((u64)__float_as_uint(hn) << 32) | (unsigned)(t + 1),
                        __ATOMIC_RELAXED, __HIP_MEMORY_SCOPE_AGENT);
                } else {
                    if (e) vh1 = hn * ow; else vh0 = hn * ow;
                }
            }
            if (role == 3) {
                const int w = tid >> 6;
                for (int o = 32; o > 0; o >>= 1) {
                    vh0 += __shfl_down(vh0, o);
                    vh1 += __shfl_down(vh1, o);
                }
                if ((tid & 63) == 0) { sRed[w] = vh0; sRed[8 + w] = vh1; }
                __syncthreads();
                if (tid < 4) {
                    const float s = sRed[tid * 4] + sRed[tid * 4 + 1]
                                  + sRed[tid * 4 + 2] + sRed[tid * 4 + 3];
                    atomicAdd(&out[(size_t)(rowbase + tid) * Tt + t],
                              s + (chain ? outb0 : 0.0f));
                }
            }
        }
        __syncthreads();   // sAh/sG/sP/sRed safe for next iteration
    }
}

extern "C" void kernel_launch(void* const* d_in, const int* in_sizes, int n_in,
                              void* d_out, int out_size, void* d_ws, size_t ws_size,
                              hipStream_t stream) {
    const float* x       = (const float*)d_in[0];
    const int*   lengths = (const int*)d_in[1];
    const float* gW0  = (const float*)d_in[2];
    const float* gU0  = (const float*)d_in[3];
    const float* gbi0 = (const float*)d_in[4];
    const float* gbr0 = (const float*)d_in[5];
    const float* gW1  = (const float*)d_in[6];
    const float* gU1  = (const float*)d_in[7];
    const float* gbi1 = (const float*)d_in[8];
    const float* gbr1 = (const float*)d_in[9];
    const float* lW0  = (const float*)d_in[10];
    const float* lU0  = (const float*)d_in[11];
    const float* lb0  = (const float*)d_in[12];
    const float* lW1  = (const float*)d_in[13];
    const float* lU1  = (const float*)d_in[14];
    const float* lb1  = (const float*)d_in[15];
    const float* outW = (const float*)d_in[16];
    const float* outb = (const float*)d_in[17];
    float* out = (float*)d_out;
    char* wsb  = (char*)d_ws;

    hipMemsetAsync(d_ws, 0, OFF_FLG + (16 << 10), stream);
    hipMemsetAsync(d_out, 0, (size_t)out_size * sizeof(float), stream);

    unsigned* W16 = (unsigned*)(wsb + OFF_W16);
    struct { const float* s; size_t o; int K; int ld; } cv[8] = {
        {gW0, oGW0, 96, 768}, {gU0, oGU0, 256, 768},
        {gW1, oGW1, 256, 768}, {gU1, oGU1, 256, 768},
        {lW0, oLW0, 96, 1024}, {lU0, oLU0, 256, 1024},
        {lW1, oLW1, 256, 1024}, {lU1, oLU1, 256, 1024},
    };
    for (int i = 0; i < 8; ++i) {
        const int n = (cv[i].K / 2) * cv[i].ld;
        cvt_pair<<<(n + 255) / 256, 256, 0, stream>>>(cv[i].s, W16 + cv[i].o, n, cv[i].ld);
    }

    rnn_persist<<<dim3(128), dim3(512), 0, stream>>>(
        x, lengths, gbi0, gbr0, gbi1, gbr1, lb0, lb1, outW, outb, out, wsb);
}

// Round 11
// 5816.204 us; speedup vs baseline: 6.4198x; 6.4198x over previous
//
#include <hip/hip_runtime.h>
#include <hip/hip_fp16.h>

// B=64, T=512, D=96, H=256
constexpr int Tt = 512, Dd = 96, Hh = 256;
constexpr int NS0 = 16;   // h0 ring depth
constexpr int NSP = 8;    // P ring depth
typedef unsigned long long u64;

// ws byte offsets (same as R9):
constexpr size_t OFF_P0  = (size_t)4 << 20;
constexpr size_t OFF_P1  = (size_t)12 << 20;
constexpr size_t OFF_FLG = (size_t)20 << 20;
constexpr size_t OFF_W16 = ((size_t)20 << 20) + ((size_t)64 << 10);
constexpr size_t oGW0 = 0;
constexpr size_t oGU0 = oGW0 + (size_t)48 * 768;
constexpr size_t oGW1 = oGU0 + (size_t)128 * 768;
constexpr size_t oGU1 = oGW1 + (size_t)128 * 768;
constexpr size_t oLW0 = oGU1 + (size_t)128 * 768;
constexpr size_t oLU0 = oLW0 + (size_t)48 * 1024;
constexpr size_t oLW1 = oLU0 + (size_t)128 * 1024;
constexpr size_t oLU1 = oLW1 + (size_t)128 * 1024;

__device__ __forceinline__ float sigf(float v) { return 1.0f / (1.0f + __expf(-v)); }
__device__ __forceinline__ u64 agld(const u64* p) {
    return __hip_atomic_load(p, __ATOMIC_RELAXED, __HIP_MEMORY_SCOPE_AGENT);
}
__device__ __forceinline__ int agldi(const int* p) {
    return __hip_atomic_load(p, __ATOMIC_ACQUIRE, __HIP_MEMORY_SCOPE_AGENT);
}

// fp16x2 dot into f32 accumulator (v_dot2_f32_f16)
__device__ __forceinline__ float dot2f(unsigned w, unsigned a, float acc) {
#if __has_builtin(__builtin_amdgcn_fdot2)
    typedef _Float16 h2v __attribute__((ext_vector_type(2)));
    h2v wh, ah;
    __builtin_memcpy(&wh, &w, 4);
    __builtin_memcpy(&ah, &a, 4);
    return __builtin_amdgcn_fdot2(wh, ah, acc, false);
#else
    const float2 wf = __half22float2(*(const __half2*)&w);
    const float2 af = __half22float2(*(const __half2*)&a);
    acc = fmaf(wf.x, af.x, acc);
    return fmaf(wf.y, af.y, acc);
#endif
}

// LDS A layout: uint4 per kp; .x/.y/.z/.w = rows 0..3, each a half2 (k=2kp, 2kp+1)
__device__ __forceinline__ int hidx(int k, int r) {
    return (k >> 1) * 8 + r * 2 + (k & 1);   // half index into sAh
}

// ---- fp16-pair GEMM, R9 structure: 4-kp chunks, depth-2 pipeline ----
template<int G>
__device__ __forceinline__ void load4h(unsigned* wv, const unsigned* __restrict__ M,
                                       int ldm, int kpb) {
    #pragma unroll
    for (int u = 0; u < 4; ++u)
        #pragma unroll
        for (int g = 0; g < G; ++g)
            wv[u * G + g] = M[(size_t)(kpb + u) * ldm + g * 256];
}
template<int G>
__device__ __forceinline__ void fma4h(const unsigned* wv, const uint4* __restrict__ A4,
                                      int kpb, float4* acc) {
    #pragma unroll
    for (int u = 0; u < 4; ++u) {
        const uint4 a = A4[kpb + u];
        #pragma unroll
        for (int g = 0; g < G; ++g) {
            const unsigned w = wv[u * G + g];
            acc[g].x = dot2f(w, a.x, acc[g].x);
            acc[g].y = dot2f(w, a.y, acc[g].y);
            acc[g].z = dot2f(w, a.z, acc[g].z);
            acc[g].w = dot2f(w, a.w, acc[g].w);
        }
    }
}
template<int G>
__device__ __forceinline__ void gemmP(const unsigned* __restrict__ M, int ldm,
                                      const uint4* __restrict__ A4,
                                      int kp0, int kp1, float4* acc) {
    const int n4 = (kp1 - kp0) >> 2;
    unsigned wv0[4 * G], wv1[4 * G];
    if (n4 <= 0) return;
    load4h<G>(wv0, M, ldm, kp0);
    int c2 = 0;
    for (; c2 + 2 <= n4; c2 += 2) {
        load4h<G>(wv1, M, ldm, kp0 + (c2 + 1) * 4);
        fma4h<G>(wv0, A4, kp0 + c2 * 4, acc);
        if (c2 + 2 < n4) load4h<G>(wv0, M, ldm, kp0 + (c2 + 2) * 4);
        fma4h<G>(wv1, A4, kp0 + (c2 + 1) * 4, acc);
    }
    if (c2 < n4) fma4h<G>(wv0, A4, kp0 + c2 * 4, acc);
}

// weight f32 -> paired fp16 (per launch)
__global__ void cvt_pair(const float* __restrict__ src, unsigned* __restrict__ dst,
                         int n, int ld) {
    const int i = blockIdx.x * 256 + threadIdx.x;
    if (i >= n) return;
    const int kp = i / ld, col = i - kp * ld;
    const __half2 h = __floats2half2_rn(src[(2 * kp) * ld + col],
                                        src[(2 * kp + 1) * ld + col]);
    dst[i] = *(const unsigned*)&h;
}

// roles: 0 = p0 (x->P0), 1 = r0 (U0 + h0 update), 2 = p1 (h0->P1), 3 = r1 (U1 + head)
// bx = (chain*4+role) + 8*rg   [R9 mapping]
__global__ void __launch_bounds__(512, 1)
rnn_persist(const float* __restrict__ x, const int* __restrict__ lengths,
            const float* __restrict__ gbi0, const float* __restrict__ gbr0,
            const float* __restrict__ gbi1, const float* __restrict__ gbr1,
            const float* __restrict__ lb0, const float* __restrict__ lb1,
            const float* __restrict__ outW, const float* __restrict__ outb,
            float* __restrict__ out, char* __restrict__ wsb)
{
    const int tid = threadIdx.x;
    const int c   = tid & 255;
    const int grp = tid >> 8;
    const int bx  = blockIdx.x;
    const int role  = bx & 3;
    const int chain = (bx >> 2) & 1;
    const int rg    = bx >> 3;
    const int rowbase = rg * 4;

    const int GA  = chain ? 4 : 3;
    const int GAH = GA * Hh;

    u64* h0ring = (u64*)wsb + (size_t)(chain * 16 + rg) * (NS0 * 1024);
    u64* p0ring = (u64*)(wsb + OFF_P0) + (size_t)(chain * 16 + rg) * (NSP * 4096);
    u64* p1ring = (u64*)(wsb + OFF_P1) + (size_t)(chain * 16 + rg) * (NSP * 4096);
    int* flags = (int*)(wsb + OFF_FLG);
    int* flg_r0 = flags + ((chain * 16 + rg) * 4 + 1) * 32;
    int* flg_p1 = flags + ((chain * 16 + rg) * 4 + 2) * 32;
    int* flg_r1 = flags + ((chain * 16 + rg) * 4 + 3) * 32;

    const unsigned* W16 = (const unsigned*)(wsb + OFF_W16);
    size_t woff;
    if (chain == 0) woff = (role == 0) ? oGW0 : (role == 1) ? oGU0 : (role == 2) ? oGW1 : oGU1;
    else            woff = (role == 0) ? oLW0 : (role == 1) ? oLU0 : (role == 2) ? oLW1 : oLU1;
    const unsigned* Mc = W16 + woff + c;

    const int KR  = (role == 0) ? Dd : Hh;
    const int KP2 = KR >> 2;                 // kp per group (24 or 64)
    const int kp0 = grp * KP2, kp1 = kp0 + KP2;

    __shared__ __align__(16) unsigned sAh[128 * 4];   // uint4[kp]: rows' half2
    __shared__ float sG[2 * 4096];
    __shared__ float sP[4096];
    __shared__ float sRed[16];
    __half* sAhh = (__half*)sAh;
    const uint4* A4 = (const uint4*)sAh;

    const int NP  = 4 * GAH;
    const int npt = NP >> 9;                 // 6 or 8
    float biasv[8];
    int sgidx[8];
    if (role == 0 || role == 2) {
        const float* bsrc = (chain == 0) ? (role == 0 ? gbi0 : gbi1)
                                         : (role == 0 ? lb0 : lb1);
        #pragma unroll
        for (int i = 0; i < 8; ++i) {
            if (i < npt) {
                const int e = tid + i * 512;
                const int r = e / GAH, rem = e - r * GAH;
                biasv[i] = bsrc[rem];
                sgidx[i] = r * 1024 + rem;
            } else { biasv[i] = 0; sgidx[i] = 0; }
        }
    }
    const int rA = tid >> 8;                 // rows rA, rA+2
    const int lenA = lengths[rowbase + rA];
    const int lenB = lengths[rowbase + rA + 2];
    float brz = 0, brr = 0, brh = 0, ow = 0;
    if (chain == 0 && (role == 1 || role == 3)) {
        const float* br = (role == 1) ? gbr0 : gbr1;
        brz = br[c]; brr = br[Hh + c]; brh = br[2 * Hh + c];
    }
    if (role == 3) ow = outW[chain * Hh + c];
    const float outb0 = outb[0];
    float creg0 = 0.0f, creg1 = 0.0f;
    float hprev0 = 0.0f, hprev1 = 0.0f;      // own h(t-1) f32 (exact masking)

    for (int i = tid; i < 512; i += 512) sAh[i] = 0;   // h(-1)=0
    __syncthreads();

    for (int t = 0; t < Tt; ++t) {
        // =========== PHASE 1: acquire input / anti-clobber (R9 order) ===========
        if (role == 0) {
            if (t >= NSP) {
                if (tid == 0)
                    while (agldi(flg_r0) < t - NSP + 1) __builtin_amdgcn_s_sleep(1);
                __syncthreads();
            }
            if (tid < 4 * Dd) {
                const int r = tid / Dd, k = tid - r * Dd;
                const float v = x[((size_t)(rowbase + r) * Tt + t) * Dd + k];
                sAhh[hidx(k, r)] = __float2half(v);
            }
            __syncthreads();
        } else if (role == 2) {
            const u64* base = h0ring + (size_t)(t & (NS0 - 1)) * 1024;
            const unsigned want = (unsigned)(t + 1);
            const int r0i = rA, r1i = rA + 2;
            const u64* p0 = base + r0i * 256 + c;
            const u64* p1 = base + r1i * 256 + c;
            u64 v0 = 0, v1 = 0; bool d0 = false, d1 = false;
            do {
                if (!d0) { v0 = agld(p0); d0 = ((unsigned)v0 == want); }
                if (!d1) { v1 = agld(p1); d1 = ((unsigned)v1 == want); }
            } while (!(d0 && d1));
            sAhh[hidx(c, r0i)] = __float2half(__uint_as_float((unsigned)(v0 >> 32)));
            sAhh[hidx(c, r1i)] = __float2half(__uint_as_float((unsigned)(v1 >> 32)));
            __syncthreads();
            if (tid == 0)
                __hip_atomic_exchange(flg_p1, t + 1, __ATOMIC_RELEASE,
                                      __HIP_MEMORY_SCOPE_AGENT);
        } else {
            // r0 / r1: poll the P slot into sP (R9: poll BEFORE GEMM)
            const u64* slot = ((role == 1) ? p0ring : p1ring)
                              + (size_t)(t & (NSP - 1)) * 4096;
            const unsigned want = (unsigned)(t + 1);
            unsigned dm = 0;
            const unsigned full = (1u << npt) - 1u;
            while (dm != full) {
                for (int i = 0; i < npt; ++i) {
                    if (!(dm & (1u << i))) {
                        const u64 v = agld(slot + tid + i * 512);
                        if ((unsigned)v == want) {
                            sP[tid + i * 512] = __uint_as_float((unsigned)(v >> 32));
                            dm |= 1u << i;
                        }
                    }
                }
            }
            __syncthreads();
            if (tid == 0)
                __hip_atomic_exchange((role == 1) ? flg_r0 : flg_r1, t + 1,
                                      __ATOMIC_RELEASE, __HIP_MEMORY_SCOPE_AGENT);
        }

        // =========== PHASE 2: GEMM (fp16 dot2) ===========
        {
            if (chain == 0) {
                float4 acc[3] = {{0,0,0,0},{0,0,0,0},{0,0,0,0}};
                gemmP<3>(Mc, GAH, A4, kp0, kp1, acc);
                #pragma unroll
                for (int g = 0; g < 3; ++g) {
                    sG[grp * 4096 + 0 + g * 256 + c]    = acc[g].x;
                    sG[grp * 4096 + 1024 + g * 256 + c] = acc[g].y;
                    sG[grp * 4096 + 2048 + g * 256 + c] = acc[g].z;
                    sG[grp * 4096 + 3072 + g * 256 + c] = acc[g].w;
                }
            } else {
                float4 acc[4] = {{0,0,0,0},{0,0,0,0},{0,0,0,0},{0,0,0,0}};
                gemmP<4>(Mc, GAH, A4, kp0, kp1, acc);
                #pragma unroll
                for (int g = 0; g < 4; ++g) {
                    sG[grp * 4096 + 0 + g * 256 + c]    = acc[g].x;
                    sG[grp * 4096 + 1024 + g * 256 + c] = acc[g].y;
                    sG[grp * 4096 + 2048 + g * 256 + c] = acc[g].z;
                    sG[grp * 4096 + 3072 + g * 256 + c] = acc[g].w;
                }
            }
        }
        __syncthreads();

        // =========== PHASE 3: publish (p) / update (r) (R9 order) ===========
        if (role == 0 || role == 2) {
            if (role == 2 && t >= NSP) {
                if (tid == 0)
                    while (agldi(flg_r1) < t - NSP + 1) __builtin_amdgcn_s_sleep(1);
                __syncthreads();
            }
            u64* ring = (role == 0) ? p0ring : p1ring;
            u64* slot = ring + (size_t)(t & (NSP - 1)) * 4096;
            for (int i = 0; i < npt; ++i) {
                const float v = sG[sgidx[i]] + sG[4096 + sgidx[i]] + biasv[i];
                atomicExch(slot + tid + i * 512,
                           ((u64)__float_as_uint(v) << 32) | (unsigned)(t + 1));
            }
        } else {
            if (role == 1 && t >= NS0) {
                if (tid == 0)
                    while (agldi(flg_p1) < t - NS0 + 1) __builtin_amdgcn_s_sleep(1);
                __syncthreads();
            }
            float vh0 = 0.0f, vh1 = 0.0f;
            #pragma unroll
            for (int e = 0; e < 2; ++e) {
                const int r = rA + e * 2;
                const float hold = e ? hprev1 : hprev0;
                const int len = e ? lenB : lenA;
                float hn;
                if (chain == 0) {
                    const float Pz = sP[r * GAH + c];
                    const float Pr = sP[r * GAH + Hh + c];
                    const float Ph = sP[r * GAH + 2 * Hh + c];
                    const float Qz = sG[r * 1024 + c]       + sG[4096 + r * 1024 + c];
                    const float Qr = sG[r * 1024 + 256 + c] + sG[4096 + r * 1024 + 256 + c];
                    const float Qh = sG[r * 1024 + 512 + c] + sG[4096 + r * 1024 + 512 + c];
                    const float z  = sigf(Pz + Qz + brz);
                    const float rr = sigf(Pr + Qr + brr);
                    const float hh = tanhf(Ph + rr * (Qh + brh));
                    hn = z * hold + (1.0f - z) * hh;
                    if (t >= len) hn = hold;
                } else {
                    const float gi = sP[r * GAH + c]          + sG[r * 1024 + c]       + sG[4096 + r * 1024 + c];
                    const float gf = sP[r * GAH + Hh + c]     + sG[r * 1024 + 256 + c] + sG[4096 + r * 1024 + 256 + c];
                    const float gc = sP[r * GAH + 2 * Hh + c] + sG[r * 1024 + 512 + c] + sG[4096 + r * 1024 + 512 + c];
                    const float go = sP[r * GAH + 3 * Hh + c] + sG[r * 1024 + 768 + c] + sG[4096 + r * 1024 + 768 + c];
                    const float cold = e ? creg1 : creg0;
                    float cn = sigf(gf) * cold + sigf(gi) * tanhf(gc);
                    hn = sigf(go) * tanhf(cn);
                    if (t >= len) { hn = hold; cn = cold; }
                    if (e) creg1 = cn; else creg0 = cn;
                }
                if (e) hprev1 = hn; else hprev0 = hn;
                sAhh[hidx(c, r)] = __float2half(hn);     // own h(t) for next GEMM
                if (role == 1) {
                    __hip_atomic_exchange(
                        h0ring + (size_t)(t & (NS0 - 1)) * 1024 + r * 256 + c,
                        ((u64)__float_as_uint(hn) << 32) | (unsigned)(t + 1),
                        __ATOMIC_RELAXED, __HIP_MEMORY_SCOPE_AGENT);
                } else {
                    if (e) vh1 = hn * ow; else vh0 = hn * ow;
                }
            }
            if (role == 3) {
                const int w = tid >> 6;
                for (int o = 32; o > 0; o >>= 1) {
                    vh0 += __shfl_down(vh0, o);
                    vh1 += __shfl_down(vh1, o);
                }
                if ((tid & 63) == 0) { sRed[w] = vh0; sRed[8 + w] = vh1; }
                __syncthreads();
                if (tid < 4) {
                    const float s = sRed[tid * 4] + sRed[tid * 4 + 1]
                                  + sRed[tid * 4 + 2] + sRed[tid * 4 + 3];
                    atomicAdd(&out[(size_t)(rowbase + tid) * Tt + t],
                              s + (chain ? outb0 : 0.0f));
                }
            }
        }
        __syncthreads();   // sAh/sG/sP/sRed safe for next iteration
    }
}

extern "C" void kernel_launch(void* const* d_in, const int* in_sizes, int n_in,
                              void* d_out, int out_size, void* d_ws, size_t ws_size,
                              hipStream_t stream) {
    const float* x       = (const float*)d_in[0];
    const int*   lengths = (const int*)d_in[1];
    const float* gW0  = (const float*)d_in[2];
    const float* gU0  = (const float*)d_in[3];
    const float* gbi0 = (const float*)d_in[4];
    const float* gbr0 = (const float*)d_in[5];
    const float* gW1  = (const float*)d_in[6];
    const float* gU1  = (const float*)d_in[7];
    const float* gbi1 = (const float*)d_in[8];
    const float* gbr1 = (const float*)d_in[9];
    const float* lW0  = (const float*)d_in[10];
    const float* lU0  = (const float*)d_in[11];
    const float* lb0  = (const float*)d_in[12];
    const float* lW1  = (const float*)d_in[13];
    const float* lU1  = (const float*)d_in[14];
    const float* lb1  = (const float*)d_in[15];
    const float* outW = (const float*)d_in[16];
    const float* outb = (const float*)d_in[17];
    float* out = (float*)d_out;
    char* wsb  = (char*)d_ws;

    hipMemsetAsync(d_ws, 0, OFF_FLG + (16 << 10), stream);
    hipMemsetAsync(d_out, 0, (size_t)out_size * sizeof(float), stream);

    unsigned* W16 = (unsigned*)(wsb + OFF_W16);
    struct { const float* s; size_t o; int K; int ld; } cv[8] = {
        {gW0, oGW0, 96, 768}, {gU0, oGU0, 256, 768},
        {gW1, oGW1, 256, 768}, {gU1, oGU1, 256, 768},
        {lW0, oLW0, 96, 1024}, {lU0, oLU0, 256, 1024},
        {lW1, oLW1, 256, 1024}, {lU1, oLU1, 256, 1024},
    };
    for (int i = 0; i < 8; ++i) {
        const int n = (cv[i].K / 2) * cv[i].ld;
        cvt_pair<<<(n + 255) / 256, 256, 0, stream>>>(cv[i].s, W16 + cv[i].o, n, cv[i].ld);
    }

    rnn_persist<<<dim3(128), dim3(512), 0, stream>>>(
        x, lengths, gbi0, gbr0, gbi1, gbr1, lb0, lb1, outW, outb, out, wsb);
}